// Round 1
// baseline (41.878 us; speedup 1.0000x reference)
//
#include <hip/hip_runtime.h>

#define RW 25            // floats per row: K + 24 LSP frequencies
#define RPB 256          // rows per block (== threads per block)

__global__ __launch_bounds__(256) void lsp2lpc_kernel(const float* __restrict__ in,
                                                      float* __restrict__ out) {
    __shared__ float sm[RPB * RW];   // 25.6 KB -> ~6 blocks/CU
    const long long row0 = (long long)blockIdx.x * RPB;
    const float* gin  = in  + row0 * RW;
    float*       gout = out + row0 * RW;
    const int tid = threadIdx.x;

    // coalesced global->LDS staging: 6400 consecutive floats
    #pragma unroll
    for (int i = 0; i < RW; ++i)
        sm[tid + i * RPB] = gin[tid + i * RPB];
    __syncthreads();

    // each thread owns one row in LDS (stride 25: conflict-free, gcd(25,32)=1)
    const float* wr = &sm[tid * RW];
    const float K = wr[0];

    // P,Q monic polys in descending powers; leading coeff at index 0.
    float P[RW], Q[RW];
    #pragma unroll
    for (int j = 0; j < RW; ++j) { P[j] = 0.f; Q[j] = 0.f; }
    P[0] = 1.f; Q[0] = 1.f;

    // multiply in one conjugate-pair quadratic (x^2 + a x + 1) at a time:
    //   new[j] = old[j] + a*old[j-1] + old[j-2], iterate j descending (in place).
    // p = wf[1::2] -> w[2],w[4],...,w[24];  q = wf[0::2] -> w[1],w[3],...,w[23]
    #pragma unroll
    for (int k = 0; k < 12; ++k) {
        const float ap = -2.f * __cosf(wr[2 + 2 * k]);
        const float aq = -2.f * __cosf(wr[1 + 2 * k]);
        #pragma unroll
        for (int j = 2 * k + 2; j >= 2; --j) {
            P[j] = P[j] + ap * P[j - 1] + P[j - 2];
            Q[j] = Q[j] + aq * Q[j - 1] + Q[j - 2];
        }
        P[1] += ap * P[0];
        Q[1] += aq * Q[0];
    }

    // epilogue: a[i] = 0.5*((P[i+1]-P[i]) + (Q[i+1]+Q[i])) ; out row = [K, a]
    // write into own LDS row (only this thread ever reads it -> no barrier needed
    // before the write; barrier needed before the cross-thread coalesced store).
    float* orow = &sm[tid * RW];
    orow[0] = K;
    #pragma unroll
    for (int i = 0; i < 24; ++i)
        orow[1 + i] = 0.5f * ((P[i + 1] - P[i]) + (Q[i + 1] + Q[i]));
    __syncthreads();

    #pragma unroll
    for (int i = 0; i < RW; ++i)
        gout[tid + i * RPB] = sm[tid + i * RPB];
}

extern "C" void kernel_launch(void* const* d_in, const int* in_sizes, int n_in,
                              void* d_out, int out_size, void* d_ws, size_t ws_size,
                              hipStream_t stream) {
    const float* in = (const float*)d_in[0];
    float* out = (float*)d_out;
    const int nrows = in_sizes[0] / RW;          // 16*65536 = 1,048,576
    const int nblocks = nrows / RPB;             // 4096 (exactly divisible)
    lsp2lpc_kernel<<<nblocks, RPB, 0, stream>>>(in, out);
}